// Round 5
// baseline (224.738 us; speedup 1.0000x reference)
//
#include <hip/hip_runtime.h>

// SSIM loss, fused, fp32, row-PAIRED packed math (v_pk_*_f32 via f32x2).
// 4096 single-wave blocks; each wave owns 32 rows x 64 cols (1 col/lane,
// 2 rows processed together as f32x2). 22 staged row-pairs, full unroll.
// No barriers anywhere; LDS is wave-private.

typedef float f32x2 __attribute__((ext_vector_type(2)));

#define IMG_W 256
#define IMG_H 256
#define N_PIX (128.0f * 256.0f * 256.0f)
#define NPAIR 22  // staged row-pairs: rows rs-6 .. rs+37

static __device__ __forceinline__ f32x2 fma2(f32x2 a, f32x2 b, f32x2 c) {
  return __builtin_elementwise_fma(a, b, c);
}

__global__ void ssim_init(float* out) { out[0] = 1.0f; }

__global__ __launch_bounds__(64, 3) void ssim_main(
    const float* __restrict__ img1, const float* __restrict__ img2,
    float* __restrict__ out) {
  // 1D Gaussian, sigma=1.5 (same constants as the passing round-2/3 kernels)
  const float W0 = 0.00102838f, W1 = 0.00759873f, W2 = 0.03600077f,
              W3 = 0.10936070f, W4 = 0.21300543f, W5 = 0.26601173f,
              W6 = 0.21300543f, W7 = 0.10936070f, W8 = 0.03600077f,
              W9 = 0.00759873f, W10 = 0.00102838f;
  const float WH[11] = {W0, W1, W2, W3, W4, W5, W6, W7, W8, W9, W10};
  // vertical weight pairs: out0 (even row) and out1 (odd row) parities
  const f32x2 CV0[5] = {{W1, W2}, {W3, W4}, {W5, W6}, {W7, W8}, {W9, W10}};
  const f32x2 CV1[5] = {{W0, W1}, {W2, W3}, {W4, W5}, {W6, W7}, {W8, W9}};

  __shared__ f32x2 LSX[2][128];  // [dbuf][col entry] row-pair of img1
  __shared__ f32x2 LSY[2][128];  // row-pair of img2

  const int lane = threadIdx.x;  // 0..63, block == one wave
  const int gw = blockIdx.x;     // 0..4095 (uniform/SGPR)
  const int img = gw >> 5;       // 32 waves per image
  const int rem = gw & 31;
  const int rs = (rem >> 2) << 5;  // strip start row (0,32,..,224)
  const int cs = (rem & 3) << 6;   // col segment (0,64,128,192)
  const int r0p = rs - 6;          // first staged row (pair-aligned)
  const char* q1 = (const char*)(img1 + (size_t)img * (IMG_W * IMG_H));
  const char* q2 = (const char*)(img2 + (size_t)img * (IMG_W * IMG_H));

  // per-lane column byte offsets (clamped) + masks; row-invariant
  const int c0 = cs - 8 + lane;  // only underflow possible
  const int c1 = c0 + 64;        // only overflow possible
  const float cm0 = (c0 >= 0) ? 1.f : 0.f;
  const float cm1 = (c1 < IMG_W) ? 1.f : 0.f;
  const int co0 = (c0 < 0 ? 0 : c0) << 2;
  const int co1 = (c1 > IMG_W - 1 ? IMG_W - 1 : c1) << 2;
  const f32x2 vm0 = {cm0, cm0};
  const f32x2 vm1 = {cm1, cm1};

#define CLAMPR(r) ((r) < 0 ? 0 : ((r) > IMG_H - 1 ? IMG_H - 1 : (r)))
// load row-pair P: 8 dword loads, mask cols; scalar row addresses (SALU)
#define PAIRLOAD(P, X0, Y0, X1, Y1)                                           \
  do {                                                                        \
    const int ra_ = r0p + 2 * (P), rb_ = ra_ + 1;                             \
    const char* a1_ = q1 + (CLAMPR(ra_) << 10);                               \
    const char* b1_ = q1 + (CLAMPR(rb_) << 10);                               \
    const char* a2_ = q2 + (CLAMPR(ra_) << 10);                               \
    const char* b2_ = q2 + (CLAMPR(rb_) << 10);                               \
    X0 = (f32x2){*(const float*)(a1_ + co0), *(const float*)(b1_ + co0)} * vm0; \
    Y0 = (f32x2){*(const float*)(a2_ + co0), *(const float*)(b2_ + co0)} * vm0; \
    X1 = (f32x2){*(const float*)(a1_ + co1), *(const float*)(b1_ + co1)} * vm1; \
    Y1 = (f32x2){*(const float*)(a2_ + co1), *(const float*)(b2_ + co1)} * vm1; \
  } while (0)

  // ring: 8 pair-slots x 5 channels of horizontal conv results (80 VGPRs)
  f32x2 rS1[8], rS2[8], rS11[8], rS22[8], rS12[8];
  f32x2 accv = {0.f, 0.f};

  // prologue: stage pair0 into buf0; held <- pair1
  f32x2 hx0, hy0, hx1, hy1, nx0, ny0, nx1, ny1;
  PAIRLOAD(0, hx0, hy0, hx1, hy1);
  LSX[0][lane] = hx0; LSY[0][lane] = hy0;
  LSX[0][64 + lane] = hx1; LSY[0][64 + lane] = hy1;
  PAIRLOAD(1, hx0, hy0, hx1, hy1);

#pragma unroll
  for (int li = 0; li < NPAIR; ++li) {
    // (1) issue loads for pair li+2 (one full iteration of latency cover)
    if (li + 2 < NPAIR) PAIRLOAD(li + 2, nx0, ny0, nx1, ny1);
    // (2) stage held pair li+1 into the other buffer
    if (li + 1 < NPAIR) {
      const int b = (li + 1) & 1;
      LSX[b][lane] = hx0; LSY[b][lane] = hy0;
      LSX[b][64 + lane] = hx1; LSY[b][64 + lane] = hy1;
    }
    // (3) horizontal 11-tap conv on row-pair li (packed f32x2)
    {
      const f32x2* bx = &LSX[li & 1][lane];
      const f32x2* by = &LSY[li & 1][lane];
      f32x2 s1 = {0, 0}, s2 = {0, 0}, s11 = {0, 0}, s22 = {0, 0}, s12 = {0, 0};
#pragma unroll
      for (int k = 0; k < 11; ++k) {
        const f32x2 vx = bx[3 + k];
        const f32x2 vy = by[3 + k];
        const f32x2 tx = vx * WH[k];
        const f32x2 ty = vy * WH[k];
        s1 += tx; s2 += ty;
        s11 = fma2(tx, vx, s11);
        s22 = fma2(ty, vy, s22);
        s12 = fma2(tx, vy, s12);
      }
      // pair validity is all-or-nothing (even alignment) -> mask-mul
      const int ra = r0p + 2 * li;
      const float vr = ((unsigned)ra < IMG_H) ? 1.f : 0.f;
      const f32x2 vmr = {vr, vr};
      rS1[li & 7] = s1 * vmr; rS2[li & 7] = s2 * vmr;
      rS11[li & 7] = s11 * vmr; rS22[li & 7] = s22 * vmr;
      rS12[li & 7] = s12 * vmr;
    }
    // (4) vertical conv + SSIM for out-pair i = li-6 (rows rs+2i, rs+2i+1)
    if (li >= 6) {
#define SLm(m) ((li + 2 + (m)) & 7)  // ring slot of pair (i+m), compile-time
#define VERT(R, V0, V1)                              \
  do {                                               \
    f32x2 a0_ = R[SLm(1)] * CV0[0];                  \
    a0_ = fma2(CV0[1], R[SLm(2)], a0_);              \
    a0_ = fma2(CV0[2], R[SLm(3)], a0_);              \
    a0_ = fma2(CV0[3], R[SLm(4)], a0_);              \
    a0_ = fma2(CV0[4], R[SLm(5)], a0_);              \
    V0 = fmaf(W0, R[SLm(0)].y, a0_.x + a0_.y);       \
    f32x2 a1_ = R[SLm(1)] * CV1[0];                  \
    a1_ = fma2(CV1[1], R[SLm(2)], a1_);              \
    a1_ = fma2(CV1[2], R[SLm(3)], a1_);              \
    a1_ = fma2(CV1[3], R[SLm(4)], a1_);              \
    a1_ = fma2(CV1[4], R[SLm(5)], a1_);              \
    V1 = fmaf(W10, R[SLm(6)].x, a1_.x + a1_.y);      \
  } while (0)
      float m1a, m1b, m2a, m2b, e11a, e11b, e22a, e22b, e12a, e12b;
      VERT(rS1, m1a, m1b);
      VERT(rS2, m2a, m2b);
      VERT(rS11, e11a, e11b);
      VERT(rS22, e22a, e22b);
      VERT(rS12, e12a, e12b);
      const f32x2 m1 = {m1a, m1b}, m2 = {m2a, m2b};
      const f32x2 e11 = {e11a, e11b}, e22 = {e22a, e22b}, e12 = {e12a, e12b};
      const f32x2 c1v = {1e-4f, 1e-4f}, c2v = {9e-4f, 9e-4f};
      const f32x2 mu11 = m1 * m1, mu22 = m2 * m2, mu12 = m1 * m2;
      const f32x2 sg11 = e11 - mu11, sg22 = e22 - mu22, sg12 = e12 - mu12;
      const f32x2 num = (mu12 * 2.0f + c1v) * (sg12 * 2.0f + c2v);
      const f32x2 den = (mu11 + mu22 + c1v) * (sg11 + sg22 + c2v);
      float t0 = __builtin_amdgcn_rcpf(den.x);
      t0 = t0 * fmaf(-den.x, t0, 2.f);  // Newton step
      float t1 = __builtin_amdgcn_rcpf(den.y);
      t1 = t1 * fmaf(-den.y, t1, 2.f);
      accv = fma2(num, (f32x2){t0, t1}, accv);
#undef VERT
#undef SLm
    }
    hx0 = nx0; hy0 = ny0; hx1 = nx1; hy1 = ny1;
  }

  // wave reduction + one atomic per wave (4096 total, spread over kernel)
  float tot = accv.x + accv.y;
  tot += __shfl_xor(tot, 1);
  tot += __shfl_xor(tot, 2);
  tot += __shfl_xor(tot, 4);
  tot += __shfl_xor(tot, 8);
  tot += __shfl_xor(tot, 16);
  tot += __shfl_xor(tot, 32);
  if (lane == 0) atomicAdd(out, tot * (-1.0f / N_PIX));
}

extern "C" void kernel_launch(void* const* d_in, const int* in_sizes, int n_in,
                              void* d_out, int out_size, void* d_ws,
                              size_t ws_size, hipStream_t stream) {
  const float* img1 = (const float*)d_in[0];
  const float* img2 = (const float*)d_in[1];
  float* out = (float*)d_out;
  ssim_init<<<1, 1, 0, stream>>>(out);
  ssim_main<<<4096, 64, 0, stream>>>(img1, img2, out);
}

// Round 8
// 163.943 us; speedup vs baseline: 1.3708x; 1.3708x over previous
//
#include <hip/hip_runtime.h>

// SSIM loss, fused, fp32. Row-paired packed H-conv (f32x2 temporaries only),
// SCALAR float[7] even/odd ring (round-2/3-proven promotion pattern: runtime
// outer loop + #pragma unroll 7 + %7 compile-time indices). No ext_vector
// persistent arrays (round-5/7 evidence: they scratch or miscompile).
// 4096 single-wave blocks; each wave: 32 rows x 64 cols; 22 staged row-pairs.

typedef float f32x2 __attribute__((ext_vector_type(2)));

#define IMG_W 256
#define IMG_H 256
#define N_PIX (128.0f * 256.0f * 256.0f)
#define NPAIR 22  // staged row-pairs: rows rs-6 .. rs+37

static __device__ __forceinline__ f32x2 fma2(f32x2 a, f32x2 b, f32x2 c) {
  return __builtin_elementwise_fma(a, b, c);
}

__global__ void ssim_init(float* out) { out[0] = 1.0f; }

__global__ __launch_bounds__(64, 3) void ssim_main(
    const float* __restrict__ img1, const float* __restrict__ img2,
    float* __restrict__ out) {
  // 1D Gaussian, sigma=1.5, 11 taps (identical constants to passing rounds)
  const float W0 = 0.00102838f, W1 = 0.00759873f, W2 = 0.03600077f,
              W3 = 0.10936070f, W4 = 0.21300543f, W5 = 0.26601173f,
              W6 = 0.21300543f, W7 = 0.10936070f, W8 = 0.03600077f,
              W9 = 0.00759873f, W10 = 0.00102838f;
  const float WH[11] = {W0, W1, W2, W3, W4, W5, W6, W7, W8, W9, W10};

  __shared__ f32x2 LSX[2][128];  // [dbuf][col entry] row-pair of img1
  __shared__ f32x2 LSY[2][128];  // row-pair of img2

  const int lane = threadIdx.x;  // 0..63; block == one wave
  const int gw = blockIdx.x;     // 0..4095
  const int img = gw >> 5;       // 32 waves per image
  const int rem = gw & 31;
  const int rs = (rem >> 2) << 5;  // strip start row (0,32,..,224)
  const int cs = (rem & 3) << 6;   // col segment (0,64,128,192)
  const int r0p = rs - 6;          // first staged row (even)
  const char* q1 = (const char*)(img1 + (size_t)img * (IMG_W * IMG_H));
  const char* q2 = (const char*)(img2 + (size_t)img * (IMG_W * IMG_H));

  // per-lane column byte offsets (clamped) + masks; row-invariant
  const int c0 = cs - 8 + lane;  // only underflow possible
  const int c1 = c0 + 64;       // only overflow possible
  const float cm0 = (c0 >= 0) ? 1.f : 0.f;
  const float cm1 = (c1 < IMG_W) ? 1.f : 0.f;
  const int co0 = (c0 < 0 ? 0 : c0) << 2;
  const int co1 = (c1 > IMG_W - 1 ? IMG_W - 1 : c1) << 2;
  const f32x2 vm0 = {cm0, cm0};
  const f32x2 vm1 = {cm1, cm1};

#define CLAMPR(r) ((r) < 0 ? 0 : ((r) > IMG_H - 1 ? IMG_H - 1 : (r)))
#define PAIRLOAD(P, X0, Y0, X1, Y1)                                           \
  do {                                                                        \
    const int ra_ = r0p + 2 * (P), rb_ = ra_ + 1;                             \
    const char* a1_ = q1 + (CLAMPR(ra_) << 10);                               \
    const char* b1_ = q1 + (CLAMPR(rb_) << 10);                               \
    const char* a2_ = q2 + (CLAMPR(ra_) << 10);                               \
    const char* b2_ = q2 + (CLAMPR(rb_) << 10);                               \
    X0 = (f32x2){*(const float*)(a1_ + co0), *(const float*)(b1_ + co0)} * vm0; \
    Y0 = (f32x2){*(const float*)(a2_ + co0), *(const float*)(b2_ + co0)} * vm0; \
    X1 = (f32x2){*(const float*)(a1_ + co1), *(const float*)(b1_ + co1)} * vm1; \
    Y1 = (f32x2){*(const float*)(a2_ + co1), *(const float*)(b2_ + co1)} * vm1; \
  } while (0)

  // ring: 7 pair-slots x 5 channels, split even/odd as SCALAR arrays (70 f32)
  float R1e[7], R1o[7], R2e[7], R2o[7], R11e[7], R11o[7], R22e[7], R22o[7],
      R12e[7], R12o[7];
  f32x2 accv = {0.f, 0.f};

  // prologue: stage pair0 into buf0; held <- pair1
  f32x2 hx0, hy0, hx1, hy1, nx0, ny0, nx1, ny1;
  PAIRLOAD(0, hx0, hy0, hx1, hy1);
  LSX[0][lane] = hx0; LSY[0][lane] = hy0;
  LSX[0][64 + lane] = hx1; LSY[0][64 + lane] = hy1;
  PAIRLOAD(1, hx0, hy0, hx1, hy1);

  for (int bl = 0; bl < 28; bl += 7) {
#pragma unroll
    for (int u = 0; u < 7; ++u) {
      const int li = bl + u;  // pair index; slot is `u` (bl % 7 == 0)
      if (li < NPAIR) {
        // (1) issue loads for pair li+2
        if (li + 2 < NPAIR) PAIRLOAD(li + 2, nx0, ny0, nx1, ny1);
        // (2) stage held pair li+1 into the other buffer
        if (li + 1 < NPAIR) {
          f32x2* wx = &LSX[(li + 1) & 1][0];
          f32x2* wy = &LSY[(li + 1) & 1][0];
          wx[lane] = hx0; wy[lane] = hy0;
          wx[64 + lane] = hx1; wy[64 + lane] = hy1;
        }
        // (3) packed horizontal 11-tap conv on row-pair li
        {
          const f32x2* bx = &LSX[li & 1][lane];
          const f32x2* by = &LSY[li & 1][lane];
          f32x2 s1 = {0, 0}, s2 = {0, 0}, s11 = {0, 0}, s22 = {0, 0},
                s12 = {0, 0};
#pragma unroll
          for (int k = 0; k < 11; ++k) {
            const f32x2 vx = bx[3 + k];
            const f32x2 vy = by[3 + k];
            const f32x2 tx = vx * WH[k];
            const f32x2 ty = vy * WH[k];
            s1 += tx; s2 += ty;
            s11 = fma2(tx, vx, s11);
            s22 = fma2(ty, vy, s22);
            s12 = fma2(tx, vy, s12);
          }
          const int ra = r0p + 2 * li;
          const float vr = ((unsigned)ra < IMG_H) ? 1.f : 0.f;
          const f32x2 vmr = {vr, vr};
          s1 *= vmr; s2 *= vmr; s11 *= vmr; s22 *= vmr; s12 *= vmr;
          // split into scalar even/odd ring slots (index u: compile-time)
          R1e[u] = s1.x;  R1o[u] = s1.y;
          R2e[u] = s2.x;  R2o[u] = s2.y;
          R11e[u] = s11.x; R11o[u] = s11.y;
          R22e[u] = s22.x; R22o[u] = s22.y;
          R12e[u] = s12.x; R12o[u] = s12.y;
        }
        // (4) scalar vertical conv + packed SSIM for out-pair i = li-6
        if (li >= 6) {
          // slot of pair (i+m) is (u+1+m)%7 -- compile-time in u,m
#define S_(m) ((u + 1 + (m)) % 7)
          // even out-row: W0*o[s0] + sum_{m=1..5} W(2m-1)*e[sm] + W(2m)*o[sm]
          // odd  out-row: sum_{m=1..5} W(2m-2)*e[sm] + W(2m-1)*o[sm] + W10*e[s6]
#define VERT(E, O, V0, V1)                              \
  do {                                                  \
    float v0_ = W0 * O[S_(0)];                          \
    v0_ = fmaf(W1, E[S_(1)], v0_);                      \
    v0_ = fmaf(W2, O[S_(1)], v0_);                      \
    v0_ = fmaf(W3, E[S_(2)], v0_);                      \
    v0_ = fmaf(W4, O[S_(2)], v0_);                      \
    v0_ = fmaf(W5, E[S_(3)], v0_);                      \
    v0_ = fmaf(W6, O[S_(3)], v0_);                      \
    v0_ = fmaf(W7, E[S_(4)], v0_);                      \
    v0_ = fmaf(W8, O[S_(4)], v0_);                      \
    v0_ = fmaf(W9, E[S_(5)], v0_);                      \
    v0_ = fmaf(W10, O[S_(5)], v0_);                     \
    V0 = v0_;                                           \
    float v1_ = W0 * E[S_(1)];                          \
    v1_ = fmaf(W1, O[S_(1)], v1_);                      \
    v1_ = fmaf(W2, E[S_(2)], v1_);                      \
    v1_ = fmaf(W3, O[S_(2)], v1_);                      \
    v1_ = fmaf(W4, E[S_(3)], v1_);                      \
    v1_ = fmaf(W5, O[S_(3)], v1_);                      \
    v1_ = fmaf(W6, E[S_(4)], v1_);                      \
    v1_ = fmaf(W7, O[S_(4)], v1_);                      \
    v1_ = fmaf(W8, E[S_(5)], v1_);                      \
    v1_ = fmaf(W9, O[S_(5)], v1_);                      \
    v1_ = fmaf(W10, E[S_(6)], v1_);                     \
    V1 = v1_;                                           \
  } while (0)
          float m1a, m1b, m2a, m2b, e11a, e11b, e22a, e22b, e12a, e12b;
          VERT(R1e, R1o, m1a, m1b);
          VERT(R2e, R2o, m2a, m2b);
          VERT(R11e, R11o, e11a, e11b);
          VERT(R22e, R22o, e22a, e22b);
          VERT(R12e, R12o, e12a, e12b);
#undef VERT
#undef S_
          const f32x2 m1 = {m1a, m1b}, m2 = {m2a, m2b};
          const f32x2 e11 = {e11a, e11b}, e22 = {e22a, e22b},
                      e12 = {e12a, e12b};
          const f32x2 c1v = {1e-4f, 1e-4f}, c2v = {9e-4f, 9e-4f};
          const f32x2 mu11 = m1 * m1, mu22 = m2 * m2, mu12 = m1 * m2;
          const f32x2 sg11 = e11 - mu11, sg22 = e22 - mu22, sg12 = e12 - mu12;
          const f32x2 num = (mu12 * 2.0f + c1v) * (sg12 * 2.0f + c2v);
          const f32x2 den = (mu11 + mu22 + c1v) * (sg11 + sg22 + c2v);
          float t0 = __builtin_amdgcn_rcpf(den.x);
          t0 = t0 * fmaf(-den.x, t0, 2.f);  // one Newton step
          float t1 = __builtin_amdgcn_rcpf(den.y);
          t1 = t1 * fmaf(-den.y, t1, 2.f);
          accv = fma2(num, (f32x2){t0, t1}, accv);
        }
        hx0 = nx0; hy0 = ny0; hx1 = nx1; hy1 = ny1;
      }
    }
  }

  // wave reduction + one atomic per wave
  float tot = accv.x + accv.y;
  tot += __shfl_xor(tot, 1);
  tot += __shfl_xor(tot, 2);
  tot += __shfl_xor(tot, 4);
  tot += __shfl_xor(tot, 8);
  tot += __shfl_xor(tot, 16);
  tot += __shfl_xor(tot, 32);
  if (lane == 0) atomicAdd(out, tot * (-1.0f / N_PIX));
}

extern "C" void kernel_launch(void* const* d_in, const int* in_sizes, int n_in,
                              void* d_out, int out_size, void* d_ws,
                              size_t ws_size, hipStream_t stream) {
  const float* img1 = (const float*)d_in[0];
  const float* img2 = (const float*)d_in[1];
  float* out = (float*)d_out;
  ssim_init<<<1, 1, 0, stream>>>(out);
  ssim_main<<<4096, 64, 0, stream>>>(img1, img2, out);
}